// Round 1
// baseline (643.150 us; speedup 1.0000x reference)
//
#include <hip/hip_runtime.h>
#include <hip/hip_bf16.h>

// VectorQuantizer on MI355X (gfx950). Inputs fp32, output buffer fp32.
// z: [64,256,32,32] f32; E: [1024,256] f32.
// out (f32): z_q[16777216] | loss[1] | indices[65536] (float(idx), bf16-roundtrip)
//
// R7: restructure gemm_argmin around pre-converted, pre-swizzled bf16 E.
//  - convert_e: E f32 -> bf16 ONCE, laid out in MFMA fragment order
//    (group=(nt,nf,ks,hi): 16 lanes x 16B contiguous). Stored in out[0..131071]
//    (z_q region, overwritten later by gather_loss) -- no ws growth.
//  - gemm_argmin: 512 blocks x 128 rows (32 rows/wave, two A-frag halves share
//    each B-fragment -> B/LDS traffic halved). Tiles staged via
//    global_load_lds width=16 (linear copy, no cvt), double-buffered with the
//    minimum 2-phase schedule: issue next stage -> compute -> vmcnt(0)+barrier.
//    Fragment ds_reads are lane-consecutive 16B -> bank-conflict-free.
//  Scores bit-identical to R6 (same cvt per element, same MFMA, same k-order,
//  same epilogue arithmetic) -> identical candidate sets -> margin/refine
//  machinery kept verbatim.
//
// ws: [0,4) loss f32 | [4,8) full cnt | [64,4160) Se[1024] | [4352,+32K) full list

typedef __attribute__((ext_vector_type(8))) short short8;
typedef __attribute__((ext_vector_type(4))) float floatx4;

#define MARGIN 2.5e-4f
#define FULL_CAP 8192u
#define IDX_OFF 16777217

__device__ __forceinline__ unsigned short f2b(float f) {
    union { float f; unsigned int i; } x; x.f = f;
    unsigned int i = x.i;
    unsigned int r = (i + 0x7fffu + ((i >> 16) & 1u)) >> 16;  // RN-even
    return (unsigned short)r;
}
__device__ __forceinline__ float b2f(unsigned short u) {
    union { unsigned int i; float f; } x; x.i = ((unsigned int)u) << 16; return x.f;
}
__device__ __forceinline__ unsigned int bf2bits(__hip_bfloat162 h) {
    union { __hip_bfloat162 h; unsigned int u; } x; x.h = h; return x.u;
}

// numpy pairwise sum of squares, n=256 contiguous: 128+128, each with 8
// stride-8 accumulators, combine ((r0+r1)+(r2+r3))+((r4+r5)+(r6+r7)).
__device__ __forceinline__ float np_pairwise_sumsq(const float* __restrict__ a) {
    float blk[2];
    #pragma unroll
    for (int h = 0; h < 2; h++) {
        const float* p = a + h * 128;
        float r0 = __fmul_rn(p[0], p[0]), r1 = __fmul_rn(p[1], p[1]);
        float r2 = __fmul_rn(p[2], p[2]), r3 = __fmul_rn(p[3], p[3]);
        float r4 = __fmul_rn(p[4], p[4]), r5 = __fmul_rn(p[5], p[5]);
        float r6 = __fmul_rn(p[6], p[6]), r7 = __fmul_rn(p[7], p[7]);
        for (int i = 8; i < 128; i += 8) {
            r0 = __fadd_rn(r0, __fmul_rn(p[i + 0], p[i + 0]));
            r1 = __fadd_rn(r1, __fmul_rn(p[i + 1], p[i + 1]));
            r2 = __fadd_rn(r2, __fmul_rn(p[i + 2], p[i + 2]));
            r3 = __fadd_rn(r3, __fmul_rn(p[i + 3], p[i + 3]));
            r4 = __fadd_rn(r4, __fmul_rn(p[i + 4], p[i + 4]));
            r5 = __fadd_rn(r5, __fmul_rn(p[i + 5], p[i + 5]));
            r6 = __fadd_rn(r6, __fmul_rn(p[i + 6], p[i + 6]));
            r7 = __fadd_rn(r7, __fmul_rn(p[i + 7], p[i + 7]));
        }
        blk[h] = __fadd_rn(__fadd_rn(__fadd_rn(r0, r1), __fadd_rn(r2, r3)),
                           __fadd_rn(__fadd_rn(r4, r5), __fadd_rn(r6, r7)));
    }
    return __fadd_rn(blk[0], blk[1]);
}

// ---------------- kernel 1: Se[k] = np-exact sum(e_k^2) ----------------
__global__ __launch_bounds__(256) void se_kernel(const float* __restrict__ E,
                                                 float* __restrict__ Se) {
    int k = blockIdx.x * 256 + threadIdx.x;
    Se[k] = np_pairwise_sumsq(E + k * 256);
}

// ---------------- kernel 1b: E f32 -> bf16 in fragment order ----------------
// Element (n,k) -> group g = ((nt*4+nf)*8+ks)*4+hi, slot lo*8+j where
// nt=n>>6, nf=(n>>4)&3, lo=n&15, ks=k>>5, hi=(k>>3)&3, j=k&7.
// One thread per k-octet: 32768 threads.
__global__ __launch_bounds__(256) void convert_e(const float* __restrict__ E,
                                                 unsigned short* __restrict__ Ebf) {
    int t = blockIdx.x * 256 + threadIdx.x;
    int n = t >> 5;
    int oct = t & 31;                 // k-octet: k = oct*8 + j ; ks=oct>>2, hi=oct&3
    int nt = n >> 6, nf = (n >> 4) & 3, lo = n & 15;
    int g = ((nt * 4 + nf) * 8 + (oct >> 2)) * 4 + (oct & 3);
    const float* src = E + n * 256 + oct * 8;
    union { short8 s; unsigned int d[4]; } u;
    #pragma unroll
    for (int j = 0; j < 4; j++)
        u.d[j] = bf2bits(__float22bfloat162_rn(make_float2(src[2 * j], src[2 * j + 1])));
    *(short8*)(Ebf + g * 128 + lo * 8) = u.s;
}

// async linear copy of 8 KiB (one wave's share of a 32 KiB tile): 8 x
// global_load_lds width-16. LDS dest = wave-uniform base + lane*16.
__device__ __forceinline__ void stage_tile(const char* gsrc, char* ldst, int lane) {
    #pragma unroll
    for (int i = 0; i < 8; i++) {
        __builtin_amdgcn_global_load_lds(
            (const __attribute__((address_space(1))) unsigned int*)(gsrc + i * 1024 + lane * 16),
            (__attribute__((address_space(3))) unsigned int*)(ldst + i * 1024),
            16, 0, 0);
    }
}

// ---------------- kernel 2: bf16 MFMA GEMM + exact candidate argmin ----------------
// 512 blocks (128 z-rows each), 256 threads = 4 waves, 32 rows/wave (2 halves).
// Dynamic LDS: 2 x 32 KiB double-buffered E tiles.
__global__ __launch_bounds__(256) void gemm_argmin(const float* __restrict__ Z,
                                                   const unsigned short* __restrict__ Ebf,
                                                   const float* __restrict__ E,
                                                   const float* __restrict__ Se,
                                                   int* __restrict__ idx_out,
                                                   int* __restrict__ full_list,
                                                   unsigned int* __restrict__ full_cnt) {
    extern __shared__ __align__(16) char smem[];   // 2 * 32768
    const int t  = threadIdx.x;
    const int w  = t >> 6;
    const int l  = t & 63;
    const int lo = l & 15;
    const int hi = l >> 4;
    const int m0 = blockIdx.x * 128;
    const int b  = m0 >> 10;                       // 128 | 1024: never crosses b
    const int hwb = (m0 & 1023) + w * 32;

    // kick off tile-0 stage so it overlaps the (long-latency, strided) A loads
    stage_tile((const char*)Ebf + w * 8192, smem + w * 8192, l);

    // A-fragments for both 16-row halves: A[m=lo][k=hi*8+j], packed fp32->bf16
    const float* zs = Z + (size_t)b * 262144 + hwb + lo;
    short8 af[2][8];
    #pragma unroll
    for (int h = 0; h < 2; h++) {
        #pragma unroll
        for (int ks = 0; ks < 8; ks++) {
            union { short8 s; unsigned int d[4]; } u;
            #pragma unroll
            for (int j = 0; j < 4; j++) {
                float a0 = zs[h * 16 + (ks * 32 + hi * 8 + 2 * j) * 1024];
                float a1 = zs[h * 16 + (ks * 32 + hi * 8 + 2 * j + 1) * 1024];
                u.d[j] = bf2bits(__float22bfloat162_rn(make_float2(a0, a1)));
            }
            af[h][ks] = u.s;
        }
    }

    float v1[2][4], v2[2][4]; int i1[2][4];
    #pragma unroll
    for (int h = 0; h < 2; h++)
        #pragma unroll
        for (int r = 0; r < 4; r++) { v1[h][r] = -1e30f; v2[h][r] = -1e30f; i1[h][r] = 0; }

    asm volatile("s_waitcnt vmcnt(0)" ::: "memory");
    __syncthreads();

    int cur = 0;
    #pragma unroll 1
    for (int nt = 0; nt < 16; nt++) {
        if (nt < 15)
            stage_tile((const char*)Ebf + (nt + 1) * 32768 + w * 8192,
                       smem + (cur ^ 1) * 32768 + w * 8192, l);

        const char* bufc = smem + cur * 32768 + l * 16;
        #pragma unroll
        for (int nf = 0; nf < 4; nf++) {
            floatx4 a0 = (floatx4){0.f, 0.f, 0.f, 0.f};
            floatx4 a1 = (floatx4){0.f, 0.f, 0.f, 0.f};
            #pragma unroll
            for (int ks = 0; ks < 8; ks++) {
                short8 bfr = *(const short8*)(bufc + (nf * 8 + ks) * 1024);
                a0 = __builtin_amdgcn_mfma_f32_16x16x32_bf16(af[0][ks], bfr, a0, 0, 0, 0);
                a1 = __builtin_amdgcn_mfma_f32_16x16x32_bf16(af[1][ks], bfr, a1, 0, 0, 0);
            }
            int n = nt * 64 + nf * 16 + lo;
            float hse = 0.5f * Se[n];
            #pragma unroll
            for (int r = 0; r < 4; r++) {
                float s0 = a0[r] - hse;
                if (s0 > v1[0][r])      { v2[0][r] = v1[0][r]; v1[0][r] = s0; i1[0][r] = n; }
                else if (s0 > v2[0][r]) { v2[0][r] = s0; }
                float s1 = a1[r] - hse;
                if (s1 > v1[1][r])      { v2[1][r] = v1[1][r]; v1[1][r] = s1; i1[1][r] = n; }
                else if (s1 > v2[1][r]) { v2[1][r] = s1; }
            }
        }
        asm volatile("s_waitcnt vmcnt(0)" ::: "memory");
        __syncthreads();
        cur ^= 1;
    }

    // per output row: merged top-1, ballots, candidate resolution (verbatim R6
    // logic, per 16-row half h)
    #pragma unroll 1
    for (int h = 0; h < 2; h++) {
        #pragma unroll 1
        for (int r = 0; r < 4; r++) {
            float a1v = v1[h][r]; int ai = i1[h][r];
            #pragma unroll
            for (int mask = 1; mask < 16; mask <<= 1) {
                float o1 = __shfl_xor(a1v, mask);
                int   oi = __shfl_xor(ai, mask);
                if (o1 > a1v || (o1 == a1v && oi < ai)) { a1v = o1; ai = oi; }
            }
            float thresh = a1v - MARGIN;
            unsigned long long balF = __ballot(v2[h][r] >= thresh);
            unsigned long long balC = __ballot(v1[h][r] >= thresh);
            unsigned int fullq = (unsigned int)(balF >> (hi * 16)) & 0xFFFFu;
            unsigned int cm    = (unsigned int)(balC >> (hi * 16)) & 0xFFFFu;
            int m = __popc(cm);
            int rl = w * 32 + h * 16 + hi * 4 + r;
            int row = m0 + rl;

            if (fullq) {
                // a lane may hide a 3rd+ candidate: full np-exact refine later
                if (lo == 0) {
                    idx_out[row] = ai;  // placeholder, overwritten by refine_full
                    unsigned int p = atomicAdd(full_cnt, 1u);
                    if (p < FULL_CAP) full_list[p] = row;
                }
            } else if (m <= 1) {
                if (lo == 0) idx_out[row] = ai;
            } else {
                // candidate set == lane-top1s within margin (complete: any other k
                // would force its lane's top2 over thresh -> fullq). Evaluate
                // np-exactly: Sz (pairwise), dot (sequential FMA), fp32 rounding.
                const int row_hw = (m0 & 1023) + rl;
                const float* zr = Z + (size_t)b * 262144 + row_hw;
                const float* er = E + (size_t)i1[h][r] * 256;
                float dot = 0.f;
                float blk[2];
                #pragma unroll
                for (int hb = 0; hb < 2; hb++) {
                    float a8[8];
                    #pragma unroll
                    for (int q = 0; q < 8; q++) {
                        float zv = zr[(hb * 128 + q) * 1024];
                        a8[q] = __fmul_rn(zv, zv);
                        dot = __fmaf_rn(zv, er[hb * 128 + q], dot);
                    }
                    for (int i = 8; i < 128; i += 8) {
                        #pragma unroll
                        for (int q = 0; q < 8; q++) {
                            float zv = zr[(hb * 128 + i + q) * 1024];
                            a8[q] = __fadd_rn(a8[q], __fmul_rn(zv, zv));
                            dot = __fmaf_rn(zv, er[hb * 128 + i + q], dot);
                        }
                    }
                    blk[hb] = __fadd_rn(__fadd_rn(__fadd_rn(a8[0], a8[1]), __fadd_rn(a8[2], a8[3])),
                                        __fadd_rn(__fadd_rn(a8[4], a8[5]), __fadd_rn(a8[6], a8[7])));
                }
                float Sz = __fadd_rn(blk[0], blk[1]);
                float dmy = 3.4e38f; int ky = 0x7fffffff;
                if ((cm >> lo) & 1u) {
                    dmy = __fsub_rn(__fadd_rn(Sz, Se[i1[h][r]]), __fmul_rn(2.f, dot));
                    ky = i1[h][r];
                }
                #pragma unroll
                for (int mask = 1; mask < 16; mask <<= 1) {
                    float od = __shfl_xor(dmy, mask);
                    int   ok = __shfl_xor(ky, mask);
                    if (od < dmy || (od == dmy && ok < ky)) { dmy = od; ky = ok; }
                }
                if (lo == 0) idx_out[row] = ky;
            }
        }
    }
}

// ---------------- kernel 3: LDS-staged full np-exact refine ----------------
// 16 rows per group; E staged in 32-row fp32 LDS tiles; stride 258 (2-way
// bank alias only). k ascending per thread, (d,k) lexicographic reduce ->
// np.argmin first-index semantics.
__global__ __launch_bounds__(256) void refine_full(const float* __restrict__ Z,
                                                   const float* __restrict__ E,
                                                   const float* __restrict__ Se,
                                                   const unsigned int* __restrict__ cnt,
                                                   const int* __restrict__ list,
                                                   int* __restrict__ idx_out) {
    __shared__ float zl[16 * 258];
    __shared__ float els[32 * 258];
    __shared__ float szs[16];
    __shared__ int rowid[16];
    unsigned int C = *cnt;
    if (C > FULL_CAP) C = FULL_CAP;
    const int t = threadIdx.x;
    const int kk = t & 31, rr = t >> 5;
    for (unsigned int base = blockIdx.x * 16; base < C; base += gridDim.x * 16) {
        int nrows = min(16, (int)(C - base));
        __syncthreads();
        if (t < 16) rowid[t] = list[base + (t < nrows ? t : 0)];
        __syncthreads();
        for (int i = 0; i < 16; i++) {
            int n = rowid[i];
            zl[i * 258 + t] = Z[(size_t)(n >> 10) * 262144 + t * 1024 + (n & 1023)];
        }
        __syncthreads();
        if (t < 16) szs[t] = np_pairwise_sumsq(&zl[t * 258]);

        float bd0 = 3.4e38f, bd1 = 3.4e38f; int bk0 = 0x7fffffff, bk1 = 0x7fffffff;
        for (int tile = 0; tile < 32; tile++) {
            __syncthreads();
            #pragma unroll
            for (int i = 0; i < 8; i++) {
                int chunk = i * 256 + t;
                int row = chunk >> 6, x = chunk & 63;
                float4 v = *(const float4*)(E + (tile * 32 + row) * 256 + x * 4);
                float* d = &els[row * 258 + x * 4];
                d[0] = v.x; d[1] = v.y; d[2] = v.z; d[3] = v.w;
            }
            __syncthreads();
            int k = tile * 32 + kk;
            const float* e  = &els[kk * 258];
            const float* za = &zl[rr * 258];
            const float* zb = &zl[(rr + 8) * 258];
            float a0 = 0.f, a1 = 0.f;
            for (int c = 0; c < 256; c += 2) {
                float2 e2 = *(const float2*)(e + c);
                float2 x2 = *(const float2*)(za + c);
                float2 y2 = *(const float2*)(zb + c);
                a0 = __fmaf_rn(x2.x, e2.x, a0); a0 = __fmaf_rn(x2.y, e2.y, a0);
                a1 = __fmaf_rn(y2.x, e2.x, a1); a1 = __fmaf_rn(y2.y, e2.y, a1);
            }
            float sek = Se[k];
            float d0 = __fsub_rn(__fadd_rn(szs[rr], sek),     __fmul_rn(2.f, a0));
            float d1 = __fsub_rn(__fadd_rn(szs[rr + 8], sek), __fmul_rn(2.f, a1));
            if (d0 < bd0) { bd0 = d0; bk0 = k; }
            if (d1 < bd1) { bd1 = d1; bk1 = k; }
        }
        #pragma unroll
        for (int mask = 1; mask < 32; mask <<= 1) {
            float od = __shfl_xor(bd0, mask); int ok = __shfl_xor(bk0, mask);
            if (od < bd0 || (od == bd0 && ok < bk0)) { bd0 = od; bk0 = ok; }
            od = __shfl_xor(bd1, mask); ok = __shfl_xor(bk1, mask);
            if (od < bd1 || (od == bd1 && ok < bk1)) { bd1 = od; bk1 = ok; }
        }
        if (kk == 0) {
            if (rr < nrows) idx_out[rowid[rr]] = bk0;
            if (rr + 8 < nrows) idx_out[rowid[rr + 8]] = bk1;
        }
    }
}

// ---------------- kernel 4: gather z_q (f32 out), fused loss ----------------
__global__ __launch_bounds__(256) void gather_loss(const float* __restrict__ Z,
                                                   const float* __restrict__ E,
                                                   const int* __restrict__ idx,
                                                   float* __restrict__ out,
                                                   float* __restrict__ loss) {
    __shared__ int nl[1024];
    __shared__ float rs[256];
    const int t = threadIdx.x;
    const int blk = blockIdx.x;
    const int e0 = blk * 8192;
    const int b = blk >> 5;
    #pragma unroll
    for (int i = 0; i < 4; i++) nl[t + i * 256] = idx[b * 1024 + t + i * 256];
    __syncthreads();
    float ls = 0.f;
    #pragma unroll 4
    for (int i = 0; i < 32; i++) {
        int e = e0 + i * 256 + t;
        int hw = e & 1023;
        int c  = (e >> 10) & 255;
        float q = E[nl[hw] * 256 + c];
        out[e] = q;
        float d = q - Z[e];
        ls += d * d;
    }
    rs[t] = ls; __syncthreads();
    for (int s = 128; s > 0; s >>= 1) { if (t < s) rs[t] += rs[t + s]; __syncthreads(); }
    if (t == 0) atomicAdd(loss, rs[0]);
}

// ---------------- kernel 5: finalize loss + indices i32 -> float in place ----------------
__global__ __launch_bounds__(256) void finalize(const float* __restrict__ loss,
                                                float* __restrict__ out) {
    int g = blockIdx.x * 256 + threadIdx.x;
    if (g == 0) out[16777216] = 1.25f * (*loss) / 16777216.f;
    int raw = ((const int*)(out + IDX_OFF))[g];
    out[IDX_OFF + g] = b2f(f2b((float)raw));  // bf16 round-trip matches bf16-cast ref
}

extern "C" void kernel_launch(void* const* d_in, const int* in_sizes, int n_in,
                              void* d_out, int out_size, void* d_ws, size_t ws_size,
                              hipStream_t stream) {
    const float* Z = (const float*)d_in[0];
    const float* E = (const float*)d_in[1];
    float* out = (float*)d_out;
    char* ws = (char*)d_ws;
    float*        loss = (float*)ws;
    unsigned int* cnt  = (unsigned int*)(ws + 4);
    float*        Se   = (float*)(ws + 64);
    int*          list = (int*)(ws + 4352);
    int*          idx  = (int*)(out + IDX_OFF);
    // bf16 fragment-ordered E lives in the z_q output region (512 KiB),
    // consumed by gemm_argmin, overwritten afterwards by gather_loss.
    unsigned short* Ebf = (unsigned short*)out;

    hipMemsetAsync(ws, 0, 8, stream);
    se_kernel<<<4, 256, 0, stream>>>(E, Se);
    convert_e<<<128, 256, 0, stream>>>(E, Ebf);
    gemm_argmin<<<512, 256, 65536, stream>>>(Z, Ebf, E, Se, idx, list, cnt);
    refine_full<<<256, 256, 0, stream>>>(Z, E, Se, cnt, list, idx);
    gather_loss<<<2048, 256, 0, stream>>>(Z, E, idx, out, loss);
    finalize<<<256, 256, 0, stream>>>(loss, out);
}

// Round 2
// 595.748 us; speedup vs baseline: 1.0796x; 1.0796x over previous
//
#include <hip/hip_runtime.h>
#include <hip/hip_bf16.h>

// VectorQuantizer on MI355X (gfx950). Inputs fp32, output buffer fp32.
// z: [64,256,32,32] f32; E: [1024,256] f32.
// out (f32): z_q[16777216] | loss[1] | indices[65536] (float(idx), bf16-roundtrip)
//
// R8: barrier-free gemm_argmin. Ebf (fragment-ordered bf16 E, 512 KB) fits in
// each XCD's 4 MB L2 -> no LDS staging at all. Each wave streams B-fragments
// directly via global_load_dwordx4 (1 KB/wave-inst, coalesced), software-
// pipelined with two named 8-fragment buffers (compile-time indexed). Zero
// __syncthreads / vmcnt(0) in the main loop. Register budget ~185 (R7's spill
// came from 256-cap overflow: af[2][8] + 32 hoisted ds_reads).
// Scores bit-identical to R6/R7 (same cvt bits, same per-(nt,nf) MFMA chain
// order) -> validated margin/ballot/refine machinery verbatim.
//
// ws: [0,4) loss f32 | [4,8) full cnt | [64,4160) Se[1024] | [4352,+32K) full list

typedef __attribute__((ext_vector_type(8))) short short8;
typedef __attribute__((ext_vector_type(4))) float floatx4;

#define MARGIN 2.5e-4f
#define FULL_CAP 8192u
#define IDX_OFF 16777217

__device__ __forceinline__ unsigned short f2b(float f) {
    union { float f; unsigned int i; } x; x.f = f;
    unsigned int i = x.i;
    unsigned int r = (i + 0x7fffu + ((i >> 16) & 1u)) >> 16;  // RN-even
    return (unsigned short)r;
}
__device__ __forceinline__ float b2f(unsigned short u) {
    union { unsigned int i; float f; } x; x.i = ((unsigned int)u) << 16; return x.f;
}
__device__ __forceinline__ unsigned int bf2bits(__hip_bfloat162 h) {
    union { __hip_bfloat162 h; unsigned int u; } x; x.h = h; return x.u;
}

// numpy pairwise sum of squares, n=256 contiguous: 128+128, each with 8
// stride-8 accumulators, combine ((r0+r1)+(r2+r3))+((r4+r5)+(r6+r7)).
__device__ __forceinline__ float np_pairwise_sumsq(const float* __restrict__ a) {
    float blk[2];
    #pragma unroll
    for (int h = 0; h < 2; h++) {
        const float* p = a + h * 128;
        float r0 = __fmul_rn(p[0], p[0]), r1 = __fmul_rn(p[1], p[1]);
        float r2 = __fmul_rn(p[2], p[2]), r3 = __fmul_rn(p[3], p[3]);
        float r4 = __fmul_rn(p[4], p[4]), r5 = __fmul_rn(p[5], p[5]);
        float r6 = __fmul_rn(p[6], p[6]), r7 = __fmul_rn(p[7], p[7]);
        for (int i = 8; i < 128; i += 8) {
            r0 = __fadd_rn(r0, __fmul_rn(p[i + 0], p[i + 0]));
            r1 = __fadd_rn(r1, __fmul_rn(p[i + 1], p[i + 1]));
            r2 = __fadd_rn(r2, __fmul_rn(p[i + 2], p[i + 2]));
            r3 = __fadd_rn(r3, __fmul_rn(p[i + 3], p[i + 3]));
            r4 = __fadd_rn(r4, __fmul_rn(p[i + 4], p[i + 4]));
            r5 = __fadd_rn(r5, __fmul_rn(p[i + 5], p[i + 5]));
            r6 = __fadd_rn(r6, __fmul_rn(p[i + 6], p[i + 6]));
            r7 = __fadd_rn(r7, __fmul_rn(p[i + 7], p[i + 7]));
        }
        blk[h] = __fadd_rn(__fadd_rn(__fadd_rn(r0, r1), __fadd_rn(r2, r3)),
                           __fadd_rn(__fadd_rn(r4, r5), __fadd_rn(r6, r7)));
    }
    return __fadd_rn(blk[0], blk[1]);
}

// ---------------- kernel 1: Se[k] = np-exact sum(e_k^2) ----------------
__global__ __launch_bounds__(256) void se_kernel(const float* __restrict__ E,
                                                 float* __restrict__ Se) {
    int k = blockIdx.x * 256 + threadIdx.x;
    Se[k] = np_pairwise_sumsq(E + k * 256);
}

// ---------------- kernel 1b: E f32 -> bf16 in fragment order ----------------
// Element (n,k) -> group g = ((nt*4+nf)*8+ks)*4+hi, slot lo*8+j where
// nt=n>>6, nf=(n>>4)&3, lo=n&15, ks=k>>5, hi=(k>>3)&3, j=k&7.
// One thread per k-octet: 32768 threads. (Layout validated by R7 pass.)
__global__ __launch_bounds__(256) void convert_e(const float* __restrict__ E,
                                                 unsigned short* __restrict__ Ebf) {
    int t = blockIdx.x * 256 + threadIdx.x;
    int n = t >> 5;
    int oct = t & 31;                 // k-octet: k = oct*8 + j ; ks=oct>>2, hi=oct&3
    int nt = n >> 6, nf = (n >> 4) & 3, lo = n & 15;
    int g = ((nt * 4 + nf) * 8 + (oct >> 2)) * 4 + (oct & 3);
    const float* src = E + n * 256 + oct * 8;
    union { short8 s; unsigned int d[4]; } u;
    #pragma unroll
    for (int j = 0; j < 4; j++)
        u.d[j] = bf2bits(__float22bfloat162_rn(make_float2(src[2 * j], src[2 * j + 1])));
    *(short8*)(Ebf + g * 128 + lo * 8) = u.s;
}

// ---------------- kernel 2: bf16 MFMA GEMM + exact candidate argmin ----------------
// 512 blocks (128 z-rows each), 256 threads = 4 waves, 32 rows/wave (2 halves
// sharing every B-fragment). No LDS, no barriers: B streamed from L2.
__global__ __launch_bounds__(256) void gemm_argmin(const float* __restrict__ Z,
                                                   const unsigned short* __restrict__ Ebf,
                                                   const float* __restrict__ E,
                                                   const float* __restrict__ Se,
                                                   int* __restrict__ idx_out,
                                                   int* __restrict__ full_list,
                                                   unsigned int* __restrict__ full_cnt) {
    const int t  = threadIdx.x;
    const int w  = t >> 6;
    const int l  = t & 63;
    const int lo = l & 15;
    const int hi = l >> 4;
    const int m0 = blockIdx.x * 128;
    const int b  = m0 >> 10;                       // 128 | 1024: never crosses b
    const int hwb = (m0 & 1023) + w * 32;

    // A-fragments for both 16-row halves: A[m=lo][k=hi*8+j], packed fp32->bf16
    const float* zs = Z + (size_t)b * 262144 + hwb + lo;
    short8 af0[8], af1[8];
    #pragma unroll
    for (int ks = 0; ks < 8; ks++) {
        union { short8 s; unsigned int d[4]; } u0, u1;
        #pragma unroll
        for (int j = 0; j < 4; j++) {
            int c = (ks * 32 + hi * 8 + 2 * j) * 1024;
            u0.d[j] = bf2bits(__float22bfloat162_rn(make_float2(zs[c], zs[c + 1024])));
            u1.d[j] = bf2bits(__float22bfloat162_rn(make_float2(zs[16 + c], zs[16 + c + 1024])));
        }
        af0[ks] = u0.s;
        af1[ks] = u1.s;
    }

    float v1[2][4], v2[2][4]; int i1[2][4];
    #pragma unroll
    for (int h = 0; h < 2; h++)
        #pragma unroll
        for (int r = 0; r < 4; r++) { v1[h][r] = -1e30f; v2[h][r] = -1e30f; i1[h][r] = 0; }

    // B-fragment stream: q = nt*4+nf in [0,64); fragment (q,ks) is 1 KB at
    // byte offset (q*8+ks)*1024, lane slice at +l*16. Two named buffers,
    // compile-time indexed; compiler pipelines the 8 loads under the MFMAs.
    const unsigned short* ebl = Ebf + l * 8;   // shorts; (q*8+ks)*512 stride

#define LOADB(buf, q_)                                                         \
    {                                                                          \
        const unsigned short* p_ = ebl + (size_t)(q_) * 4096;                  \
        _Pragma("unroll")                                                      \
        for (int ks = 0; ks < 8; ks++) buf[ks] = *(const short8*)(p_ + ks * 512); \
    }

#define COMPUTE(buf, q_)                                                       \
    {                                                                          \
        float hse = 0.5f * Se[(q_) * 16 + lo];                                 \
        floatx4 a0 = (floatx4){0.f, 0.f, 0.f, 0.f};                            \
        floatx4 a1 = (floatx4){0.f, 0.f, 0.f, 0.f};                            \
        _Pragma("unroll")                                                      \
        for (int ks = 0; ks < 8; ks++) {                                       \
            a0 = __builtin_amdgcn_mfma_f32_16x16x32_bf16(af0[ks], buf[ks], a0, 0, 0, 0); \
            a1 = __builtin_amdgcn_mfma_f32_16x16x32_bf16(af1[ks], buf[ks], a1, 0, 0, 0); \
        }                                                                      \
        int n = (q_) * 16 + lo;                                                \
        _Pragma("unroll")                                                      \
        for (int r = 0; r < 4; r++) {                                          \
            float s0 = a0[r] - hse;                                            \
            if (s0 > v1[0][r])      { v2[0][r] = v1[0][r]; v1[0][r] = s0; i1[0][r] = n; } \
            else if (s0 > v2[0][r]) { v2[0][r] = s0; }                         \
            float s1 = a1[r] - hse;                                            \
            if (s1 > v1[1][r])      { v2[1][r] = v1[1][r]; v1[1][r] = s1; i1[1][r] = n; } \
            else if (s1 > v2[1][r]) { v2[1][r] = s1; }                         \
        }                                                                      \
    }

    short8 bA[8], bB[8];
    LOADB(bA, 0)
    #pragma unroll 1
    for (int q = 0; q < 64; q += 2) {
        LOADB(bB, q + 1)
        COMPUTE(bA, q)
        if (q < 62) LOADB(bA, q + 2)
        COMPUTE(bB, q + 1)
    }
#undef LOADB
#undef COMPUTE

    // per output row: merged top-1, ballots, candidate resolution (verbatim R6
    // logic, per 16-row half h)
    #pragma unroll 1
    for (int h = 0; h < 2; h++) {
        #pragma unroll 1
        for (int r = 0; r < 4; r++) {
            float a1v = v1[h][r]; int ai = i1[h][r];
            #pragma unroll
            for (int mask = 1; mask < 16; mask <<= 1) {
                float o1 = __shfl_xor(a1v, mask);
                int   oi = __shfl_xor(ai, mask);
                if (o1 > a1v || (o1 == a1v && oi < ai)) { a1v = o1; ai = oi; }
            }
            float thresh = a1v - MARGIN;
            unsigned long long balF = __ballot(v2[h][r] >= thresh);
            unsigned long long balC = __ballot(v1[h][r] >= thresh);
            unsigned int fullq = (unsigned int)(balF >> (hi * 16)) & 0xFFFFu;
            unsigned int cm    = (unsigned int)(balC >> (hi * 16)) & 0xFFFFu;
            int m = __popc(cm);
            int rl = w * 32 + h * 16 + hi * 4 + r;
            int row = m0 + rl;

            if (fullq) {
                // a lane may hide a 3rd+ candidate: full np-exact refine later
                if (lo == 0) {
                    idx_out[row] = ai;  // placeholder, overwritten by refine_full
                    unsigned int p = atomicAdd(full_cnt, 1u);
                    if (p < FULL_CAP) full_list[p] = row;
                }
            } else if (m <= 1) {
                if (lo == 0) idx_out[row] = ai;
            } else {
                // candidate set == lane-top1s within margin (complete: any other k
                // would force its lane's top2 over thresh -> fullq). Evaluate
                // np-exactly: Sz (pairwise), dot (sequential FMA), fp32 rounding.
                const int row_hw = (m0 & 1023) + rl;
                const float* zr = Z + (size_t)b * 262144 + row_hw;
                const float* er = E + (size_t)i1[h][r] * 256;
                float dot = 0.f;
                float blk[2];
                #pragma unroll
                for (int hb = 0; hb < 2; hb++) {
                    float a8[8];
                    #pragma unroll
                    for (int q = 0; q < 8; q++) {
                        float zv = zr[(hb * 128 + q) * 1024];
                        a8[q] = __fmul_rn(zv, zv);
                        dot = __fmaf_rn(zv, er[hb * 128 + q], dot);
                    }
                    for (int i = 8; i < 128; i += 8) {
                        #pragma unroll
                        for (int q = 0; q < 8; q++) {
                            float zv = zr[(hb * 128 + i + q) * 1024];
                            a8[q] = __fadd_rn(a8[q], __fmul_rn(zv, zv));
                            dot = __fmaf_rn(zv, er[hb * 128 + i + q], dot);
                        }
                    }
                    blk[hb] = __fadd_rn(__fadd_rn(__fadd_rn(a8[0], a8[1]), __fadd_rn(a8[2], a8[3])),
                                        __fadd_rn(__fadd_rn(a8[4], a8[5]), __fadd_rn(a8[6], a8[7])));
                }
                float Sz = __fadd_rn(blk[0], blk[1]);
                float dmy = 3.4e38f; int ky = 0x7fffffff;
                if ((cm >> lo) & 1u) {
                    dmy = __fsub_rn(__fadd_rn(Sz, Se[i1[h][r]]), __fmul_rn(2.f, dot));
                    ky = i1[h][r];
                }
                #pragma unroll
                for (int mask = 1; mask < 16; mask <<= 1) {
                    float od = __shfl_xor(dmy, mask);
                    int   ok = __shfl_xor(ky, mask);
                    if (od < dmy || (od == dmy && ok < ky)) { dmy = od; ky = ok; }
                }
                if (lo == 0) idx_out[row] = ky;
            }
        }
    }
}

// ---------------- kernel 3: LDS-staged full np-exact refine ----------------
// 16 rows per group; E staged in 32-row fp32 LDS tiles; stride 258 (2-way
// bank alias only). k ascending per thread, (d,k) lexicographic reduce ->
// np.argmin first-index semantics.
__global__ __launch_bounds__(256) void refine_full(const float* __restrict__ Z,
                                                   const float* __restrict__ E,
                                                   const float* __restrict__ Se,
                                                   const unsigned int* __restrict__ cnt,
                                                   const int* __restrict__ list,
                                                   int* __restrict__ idx_out) {
    __shared__ float zl[16 * 258];
    __shared__ float els[32 * 258];
    __shared__ float szs[16];
    __shared__ int rowid[16];
    unsigned int C = *cnt;
    if (C > FULL_CAP) C = FULL_CAP;
    const int t = threadIdx.x;
    const int kk = t & 31, rr = t >> 5;
    for (unsigned int base = blockIdx.x * 16; base < C; base += gridDim.x * 16) {
        int nrows = min(16, (int)(C - base));
        __syncthreads();
        if (t < 16) rowid[t] = list[base + (t < nrows ? t : 0)];
        __syncthreads();
        for (int i = 0; i < 16; i++) {
            int n = rowid[i];
            zl[i * 258 + t] = Z[(size_t)(n >> 10) * 262144 + t * 1024 + (n & 1023)];
        }
        __syncthreads();
        if (t < 16) szs[t] = np_pairwise_sumsq(&zl[t * 258]);

        float bd0 = 3.4e38f, bd1 = 3.4e38f; int bk0 = 0x7fffffff, bk1 = 0x7fffffff;
        for (int tile = 0; tile < 32; tile++) {
            __syncthreads();
            #pragma unroll
            for (int i = 0; i < 8; i++) {
                int chunk = i * 256 + t;
                int row = chunk >> 6, x = chunk & 63;
                float4 v = *(const float4*)(E + (tile * 32 + row) * 256 + x * 4);
                float* d = &els[row * 258 + x * 4];
                d[0] = v.x; d[1] = v.y; d[2] = v.z; d[3] = v.w;
            }
            __syncthreads();
            int k = tile * 32 + kk;
            const float* e  = &els[kk * 258];
            const float* za = &zl[rr * 258];
            const float* zb = &zl[(rr + 8) * 258];
            float a0 = 0.f, a1 = 0.f;
            for (int c = 0; c < 256; c += 2) {
                float2 e2 = *(const float2*)(e + c);
                float2 x2 = *(const float2*)(za + c);
                float2 y2 = *(const float2*)(zb + c);
                a0 = __fmaf_rn(x2.x, e2.x, a0); a0 = __fmaf_rn(x2.y, e2.y, a0);
                a1 = __fmaf_rn(y2.x, e2.x, a1); a1 = __fmaf_rn(y2.y, e2.y, a1);
            }
            float sek = Se[k];
            float d0 = __fsub_rn(__fadd_rn(szs[rr], sek),     __fmul_rn(2.f, a0));
            float d1 = __fsub_rn(__fadd_rn(szs[rr + 8], sek), __fmul_rn(2.f, a1));
            if (d0 < bd0) { bd0 = d0; bk0 = k; }
            if (d1 < bd1) { bd1 = d1; bk1 = k; }
        }
        #pragma unroll
        for (int mask = 1; mask < 32; mask <<= 1) {
            float od = __shfl_xor(bd0, mask); int ok = __shfl_xor(bk0, mask);
            if (od < bd0 || (od == bd0 && ok < bk0)) { bd0 = od; bk0 = ok; }
            od = __shfl_xor(bd1, mask); ok = __shfl_xor(bk1, mask);
            if (od < bd1 || (od == bd1 && ok < bk1)) { bd1 = od; bk1 = ok; }
        }
        if (kk == 0) {
            if (rr < nrows) idx_out[rowid[rr]] = bk0;
            if (rr + 8 < nrows) idx_out[rowid[rr + 8]] = bk1;
        }
    }
}

// ---------------- kernel 4: gather z_q (f32 out), fused loss ----------------
__global__ __launch_bounds__(256) void gather_loss(const float* __restrict__ Z,
                                                   const float* __restrict__ E,
                                                   const int* __restrict__ idx,
                                                   float* __restrict__ out,
                                                   float* __restrict__ loss) {
    __shared__ int nl[1024];
    __shared__ float rs[256];
    const int t = threadIdx.x;
    const int blk = blockIdx.x;
    const int e0 = blk * 8192;
    const int b = blk >> 5;
    #pragma unroll
    for (int i = 0; i < 4; i++) nl[t + i * 256] = idx[b * 1024 + t + i * 256];
    __syncthreads();
    float ls = 0.f;
    #pragma unroll 4
    for (int i = 0; i < 32; i++) {
        int e = e0 + i * 256 + t;
        int hw = e & 1023;
        int c  = (e >> 10) & 255;
        float q = E[nl[hw] * 256 + c];
        out[e] = q;
        float d = q - Z[e];
        ls += d * d;
    }
    rs[t] = ls; __syncthreads();
    for (int s = 128; s > 0; s >>= 1) { if (t < s) rs[t] += rs[t + s]; __syncthreads(); }
    if (t == 0) atomicAdd(loss, rs[0]);
}

// ---------------- kernel 5: finalize loss + indices i32 -> float in place ----------------
__global__ __launch_bounds__(256) void finalize(const float* __restrict__ loss,
                                                float* __restrict__ out) {
    int g = blockIdx.x * 256 + threadIdx.x;
    if (g == 0) out[16777216] = 1.25f * (*loss) / 16777216.f;
    int raw = ((const int*)(out + IDX_OFF))[g];
    out[IDX_OFF + g] = b2f(f2b((float)raw));  // bf16 round-trip matches bf16-cast ref
}

extern "C" void kernel_launch(void* const* d_in, const int* in_sizes, int n_in,
                              void* d_out, int out_size, void* d_ws, size_t ws_size,
                              hipStream_t stream) {
    const float* Z = (const float*)d_in[0];
    const float* E = (const float*)d_in[1];
    float* out = (float*)d_out;
    char* ws = (char*)d_ws;
    float*        loss = (float*)ws;
    unsigned int* cnt  = (unsigned int*)(ws + 4);
    float*        Se   = (float*)(ws + 64);
    int*          list = (int*)(ws + 4352);
    int*          idx  = (int*)(out + IDX_OFF);
    // bf16 fragment-ordered E lives in the z_q output region (512 KiB),
    // consumed by gemm_argmin, overwritten afterwards by gather_loss.
    unsigned short* Ebf = (unsigned short*)out;

    hipMemsetAsync(ws, 0, 8, stream);
    se_kernel<<<4, 256, 0, stream>>>(E, Se);
    convert_e<<<128, 256, 0, stream>>>(E, Ebf);
    gemm_argmin<<<512, 256, 0, stream>>>(Z, Ebf, E, Se, idx, list, cnt);
    refine_full<<<256, 256, 0, stream>>>(Z, E, Se, cnt, list, idx);
    gather_loss<<<2048, 256, 0, stream>>>(Z, E, idx, out, loss);
    finalize<<<256, 256, 0, stream>>>(loss, out);
}

// Round 3
// 492.054 us; speedup vs baseline: 1.3071x; 1.2107x over previous
//
#include <hip/hip_runtime.h>
#include <hip/hip_bf16.h>

// VectorQuantizer on MI355X (gfx950). Inputs fp32, output buffer fp32.
// z: [64,256,32,32] f32; E: [1024,256] f32.
// out (f32): z_q[16777216] | loss[1] | indices[65536] (float(idx), bf16-roundtrip)
//
// R9: LDS-resident Z slab. R8 post-mortem: VALU-inst/wave (~26K) shows the
// inline m>=2 candidate eval runs on most quads and is latency-crippled by
// stride-4KB HBM z-reads + VGPR-starved prefetch (VGPR pinned 256, spills).
// Fix: 64-row blocks (grid 1024); stage the block's exact-fp32 Z (64KB) into
// LDS once via global_load_lds; build A-fragments, precompute per-row Sz
// (np-pairwise, wave 0), cache Se in LDS. Eval z-reads become broadcast
// ds_reads; only the E-row gathers stay global (L2). B streamed barrier-free
// from fragment-ordered Ebf in L2 (as R8, validated). af halves to 32 VGPR
// -> no spill. Scores bit-identical to R6/R7/R8 (fp32 exact through LDS,
// same cvt pairing, same MFMA chain order, same candidate partition
// n = q*16+lo) -> validated margin/ballot/refine machinery verbatim.
//
// ws: [0,4) loss f32 | [4,8) full cnt | [64,4160) Se[1024] | [4352,+32K) full list

typedef __attribute__((ext_vector_type(8))) short short8;
typedef __attribute__((ext_vector_type(4))) float floatx4;

#define MARGIN 2.5e-4f
#define FULL_CAP 8192u
#define IDX_OFF 16777217

__device__ __forceinline__ unsigned short f2b(float f) {
    union { float f; unsigned int i; } x; x.f = f;
    unsigned int i = x.i;
    unsigned int r = (i + 0x7fffu + ((i >> 16) & 1u)) >> 16;  // RN-even
    return (unsigned short)r;
}
__device__ __forceinline__ float b2f(unsigned short u) {
    union { unsigned int i; float f; } x; x.i = ((unsigned int)u) << 16; return x.f;
}
__device__ __forceinline__ unsigned int bf2bits(__hip_bfloat162 h) {
    union { __hip_bfloat162 h; unsigned int u; } x; x.h = h; return x.u;
}

// numpy pairwise sum of squares, n=256 contiguous: 128+128, each with 8
// stride-8 accumulators, combine ((r0+r1)+(r2+r3))+((r4+r5)+(r6+r7)).
__device__ __forceinline__ float np_pairwise_sumsq(const float* __restrict__ a) {
    float blk[2];
    #pragma unroll
    for (int h = 0; h < 2; h++) {
        const float* p = a + h * 128;
        float r0 = __fmul_rn(p[0], p[0]), r1 = __fmul_rn(p[1], p[1]);
        float r2 = __fmul_rn(p[2], p[2]), r3 = __fmul_rn(p[3], p[3]);
        float r4 = __fmul_rn(p[4], p[4]), r5 = __fmul_rn(p[5], p[5]);
        float r6 = __fmul_rn(p[6], p[6]), r7 = __fmul_rn(p[7], p[7]);
        for (int i = 8; i < 128; i += 8) {
            r0 = __fadd_rn(r0, __fmul_rn(p[i + 0], p[i + 0]));
            r1 = __fadd_rn(r1, __fmul_rn(p[i + 1], p[i + 1]));
            r2 = __fadd_rn(r2, __fmul_rn(p[i + 2], p[i + 2]));
            r3 = __fadd_rn(r3, __fmul_rn(p[i + 3], p[i + 3]));
            r4 = __fadd_rn(r4, __fmul_rn(p[i + 4], p[i + 4]));
            r5 = __fadd_rn(r5, __fmul_rn(p[i + 5], p[i + 5]));
            r6 = __fadd_rn(r6, __fmul_rn(p[i + 6], p[i + 6]));
            r7 = __fadd_rn(r7, __fmul_rn(p[i + 7], p[i + 7]));
        }
        blk[h] = __fadd_rn(__fadd_rn(__fadd_rn(r0, r1), __fadd_rn(r2, r3)),
                           __fadd_rn(__fadd_rn(r4, r5), __fadd_rn(r6, r7)));
    }
    return __fadd_rn(blk[0], blk[1]);
}

// same summation tree, element c at a[c*64] (LDS [c][x] layout, fixed x)
__device__ __forceinline__ float np_pairwise_sumsq_s64(const float* __restrict__ a) {
    float blk[2];
    #pragma unroll
    for (int h = 0; h < 2; h++) {
        const float* p = a + h * 128 * 64;
        float r0 = __fmul_rn(p[0 * 64], p[0 * 64]), r1 = __fmul_rn(p[1 * 64], p[1 * 64]);
        float r2 = __fmul_rn(p[2 * 64], p[2 * 64]), r3 = __fmul_rn(p[3 * 64], p[3 * 64]);
        float r4 = __fmul_rn(p[4 * 64], p[4 * 64]), r5 = __fmul_rn(p[5 * 64], p[5 * 64]);
        float r6 = __fmul_rn(p[6 * 64], p[6 * 64]), r7 = __fmul_rn(p[7 * 64], p[7 * 64]);
        for (int i = 8; i < 128; i += 8) {
            r0 = __fadd_rn(r0, __fmul_rn(p[(i + 0) * 64], p[(i + 0) * 64]));
            r1 = __fadd_rn(r1, __fmul_rn(p[(i + 1) * 64], p[(i + 1) * 64]));
            r2 = __fadd_rn(r2, __fmul_rn(p[(i + 2) * 64], p[(i + 2) * 64]));
            r3 = __fadd_rn(r3, __fmul_rn(p[(i + 3) * 64], p[(i + 3) * 64]));
            r4 = __fadd_rn(r4, __fmul_rn(p[(i + 4) * 64], p[(i + 4) * 64]));
            r5 = __fadd_rn(r5, __fmul_rn(p[(i + 5) * 64], p[(i + 5) * 64]));
            r6 = __fadd_rn(r6, __fmul_rn(p[(i + 6) * 64], p[(i + 6) * 64]));
            r7 = __fadd_rn(r7, __fmul_rn(p[(i + 7) * 64], p[(i + 7) * 64]));
        }
        blk[h] = __fadd_rn(__fadd_rn(__fadd_rn(r0, r1), __fadd_rn(r2, r3)),
                           __fadd_rn(__fadd_rn(r4, r5), __fadd_rn(r6, r7)));
    }
    return __fadd_rn(blk[0], blk[1]);
}

// ---------------- kernel 1: E f32 -> bf16 fragment order, + Se ----------------
// convert: element (n,k) -> group g = ((nt*4+nf)*8+ks)*4+hi, slot lo*8+j
// (layout validated R7/R8). Blocks 0-3 additionally compute Se[k] np-exact
// (fuses the old se_kernel launch).
__global__ __launch_bounds__(256) void convert_e(const float* __restrict__ E,
                                                 unsigned short* __restrict__ Ebf,
                                                 float* __restrict__ Se) {
    int t = blockIdx.x * 256 + threadIdx.x;
    int n = t >> 5;
    int oct = t & 31;                 // k-octet: k = oct*8 + j ; ks=oct>>2, hi=oct&3
    int nt = n >> 6, nf = (n >> 4) & 3, lo = n & 15;
    int g = ((nt * 4 + nf) * 8 + (oct >> 2)) * 4 + (oct & 3);
    const float* src = E + n * 256 + oct * 8;
    union { short8 s; unsigned int d[4]; } u;
    #pragma unroll
    for (int j = 0; j < 4; j++)
        u.d[j] = bf2bits(__float22bfloat162_rn(make_float2(src[2 * j], src[2 * j + 1])));
    *(short8*)(Ebf + g * 128 + lo * 8) = u.s;
    if (blockIdx.x < 4) {
        int k = blockIdx.x * 256 + threadIdx.x;
        Se[k] = np_pairwise_sumsq(E + k * 256);
    }
}

// ---------------- kernel 2: bf16 MFMA GEMM + exact candidate argmin ----------------
// 1024 blocks (64 z-rows each), 256 threads = 4 waves, 16 rows/wave.
// Z slab (64 rows x 256 ch fp32 = 64KB) + Se (4KB) + szs in static LDS.
__global__ __launch_bounds__(256) void gemm_argmin(const float* __restrict__ Z,
                                                   const unsigned short* __restrict__ Ebf,
                                                   const float* __restrict__ E,
                                                   const float* __restrict__ Se,
                                                   int* __restrict__ idx_out,
                                                   int* __restrict__ full_list,
                                                   unsigned int* __restrict__ full_cnt) {
    __shared__ __align__(16) float Zl[16384];   // [c][x]: c*64 + x, 64KB
    __shared__ __align__(16) float Sel[1024];
    __shared__ float szs[64];
    const int t  = threadIdx.x;
    const int w  = t >> 6;
    const int l  = t & 63;
    const int lo = l & 15;
    const int hi = l >> 4;
    const int m0 = blockIdx.x * 64;
    const int b  = m0 >> 10;                    // 64 | 1024: never crosses b
    const int hwb = m0 & 1023;
    const float* Zb = Z + (size_t)b * 262144;

    // stage Zl: 64 slots of 1KB (4 ch-rows x 256B); wave w takes slots w+4j.
    // lane l: ch = slot*4 + (l>>4), x = (l&15)*4; dest = slot*1024 + l*16 (linear).
    #pragma unroll
    for (int j = 0; j < 16; j++) {
        int iw = w + j * 4;
        __builtin_amdgcn_global_load_lds(
            (const __attribute__((address_space(1))) unsigned int*)
                (Zb + (iw * 4 + hi) * 1024 + hwb + lo * 4),
            (__attribute__((address_space(3))) unsigned int*)((char*)Zl + iw * 1024),
            16, 0, 0);
    }
    // stage Se: wave w stages floats [w*256, w*256+256)
    __builtin_amdgcn_global_load_lds(
        (const __attribute__((address_space(1))) unsigned int*)(Se + w * 256 + l * 4),
        (__attribute__((address_space(3))) unsigned int*)((char*)Sel + w * 1024),
        16, 0, 0);
    asm volatile("s_waitcnt vmcnt(0)" ::: "memory");
    __syncthreads();

    // per-row np-exact Sz (same pairwise tree), wave 0: row t
    if (t < 64) szs[t] = np_pairwise_sumsq_s64(Zl + t);

    // A-fragments from LDS: A[m=lo][k=hi*8+j], same cvt pairing -> same bits
    short8 af[8];
    {
        const float* zr = Zl + w * 16 + lo;
        #pragma unroll
        for (int ks = 0; ks < 8; ks++) {
            union { short8 s; unsigned int d[4]; } u;
            #pragma unroll
            for (int j = 0; j < 4; j++) {
                int k = ks * 32 + hi * 8 + 2 * j;
                u.d[j] = bf2bits(__float22bfloat162_rn(
                    make_float2(zr[k * 64], zr[(k + 1) * 64])));
            }
            af[ks] = u.s;
        }
    }

    float v1[4], v2[4]; int i1[4];
    #pragma unroll
    for (int r = 0; r < 4; r++) { v1[r] = -1e30f; v2[r] = -1e30f; i1[r] = 0; }

    // B-fragment stream from L2-resident Ebf (validated layout): fragment
    // (q,ks) = 1KB at (q*8+ks)*1024 bytes, lane slice +l*16.
    const unsigned short* ebl = Ebf + l * 8;

#define LOADB(buf, q_)                                                         \
    {                                                                          \
        const unsigned short* p_ = ebl + (size_t)(q_) * 4096;                  \
        _Pragma("unroll")                                                      \
        for (int ks = 0; ks < 8; ks++) buf[ks] = *(const short8*)(p_ + ks * 512); \
    }

#define COMPUTE(buf, q_)                                                       \
    {                                                                          \
        float hse = 0.5f * Sel[(q_) * 16 + lo];                                \
        floatx4 a0 = (floatx4){0.f, 0.f, 0.f, 0.f};                            \
        _Pragma("unroll")                                                      \
        for (int ks = 0; ks < 8; ks++)                                         \
            a0 = __builtin_amdgcn_mfma_f32_16x16x32_bf16(af[ks], buf[ks], a0, 0, 0, 0); \
        int n = (q_) * 16 + lo;                                                \
        _Pragma("unroll")                                                      \
        for (int r = 0; r < 4; r++) {                                          \
            float s0 = a0[r] - hse;                                            \
            if (s0 > v1[r])      { v2[r] = v1[r]; v1[r] = s0; i1[r] = n; }     \
            else if (s0 > v2[r]) { v2[r] = s0; }                               \
        }                                                                      \
    }

    short8 bA[8], bB[8];
    LOADB(bA, 0)
    #pragma unroll 1
    for (int q = 0; q < 64; q += 2) {
        LOADB(bB, q + 1)
        COMPUTE(bA, q)
        if (q < 62) LOADB(bA, q + 2)
        COMPUTE(bB, q + 1)
    }
#undef LOADB
#undef COMPUTE

    __syncthreads();   // szs visibility before eval (uniform control flow)

    // per output row: merged top-1, ballots, candidate resolution (verbatim
    // R6/R8 logic; z-reads now LDS, Sz precomputed — same bits)
    #pragma unroll 1
    for (int r = 0; r < 4; r++) {
        float a1v = v1[r]; int ai = i1[r];
        #pragma unroll
        for (int mask = 1; mask < 16; mask <<= 1) {
            float o1 = __shfl_xor(a1v, mask);
            int   oi = __shfl_xor(ai, mask);
            if (o1 > a1v || (o1 == a1v && oi < ai)) { a1v = o1; ai = oi; }
        }
        float thresh = a1v - MARGIN;
        unsigned long long balF = __ballot(v2[r] >= thresh);
        unsigned long long balC = __ballot(v1[r] >= thresh);
        unsigned int fullq = (unsigned int)(balF >> (hi * 16)) & 0xFFFFu;
        unsigned int cm    = (unsigned int)(balC >> (hi * 16)) & 0xFFFFu;
        int m = __popc(cm);
        int rl  = w * 16 + hi * 4 + r;
        int row = m0 + rl;

        if (fullq) {
            // a lane may hide a 3rd+ candidate: full np-exact refine later
            if (lo == 0) {
                idx_out[row] = ai;  // placeholder, overwritten by refine_full
                unsigned int p = atomicAdd(full_cnt, 1u);
                if (p < FULL_CAP) full_list[p] = row;
            }
        } else if (m <= 1) {
            if (lo == 0) idx_out[row] = ai;
        } else {
            // candidate set == lane-top1s within margin (complete: any other k
            // would force its lane's top2 over thresh -> fullq). np-exact:
            // Sz precomputed (same pairwise tree), dot sequential FMA c=0..255.
            const float* zrow = Zl + rl;
            const float* er = E + (size_t)i1[r] * 256;
            float dot = 0.f;
            for (int c = 0; c < 256; c++)
                dot = __fmaf_rn(zrow[c * 64], er[c], dot);
            float Sz = szs[rl];
            float dmy = 3.4e38f; int ky = 0x7fffffff;
            if ((cm >> lo) & 1u) {
                dmy = __fsub_rn(__fadd_rn(Sz, Se[i1[r]]), __fmul_rn(2.f, dot));
                ky = i1[r];
            }
            #pragma unroll
            for (int mask = 1; mask < 16; mask <<= 1) {
                float od = __shfl_xor(dmy, mask);
                int   ok = __shfl_xor(ky, mask);
                if (od < dmy || (od == dmy && ok < ky)) { dmy = od; ky = ok; }
            }
            if (lo == 0) idx_out[row] = ky;
        }
    }
}

// ---------------- kernel 3: LDS-staged full np-exact refine ----------------
// 16 rows per group; E staged in 32-row fp32 LDS tiles; stride 258 (2-way
// bank alias only). k ascending per thread, (d,k) lexicographic reduce ->
// np.argmin first-index semantics.
__global__ __launch_bounds__(256) void refine_full(const float* __restrict__ Z,
                                                   const float* __restrict__ E,
                                                   const float* __restrict__ Se,
                                                   const unsigned int* __restrict__ cnt,
                                                   const int* __restrict__ list,
                                                   int* __restrict__ idx_out) {
    __shared__ float zl[16 * 258];
    __shared__ float els[32 * 258];
    __shared__ float szs[16];
    __shared__ int rowid[16];
    unsigned int C = *cnt;
    if (C > FULL_CAP) C = FULL_CAP;
    const int t = threadIdx.x;
    const int kk = t & 31, rr = t >> 5;
    for (unsigned int base = blockIdx.x * 16; base < C; base += gridDim.x * 16) {
        int nrows = min(16, (int)(C - base));
        __syncthreads();
        if (t < 16) rowid[t] = list[base + (t < nrows ? t : 0)];
        __syncthreads();
        for (int i = 0; i < 16; i++) {
            int n = rowid[i];
            zl[i * 258 + t] = Z[(size_t)(n >> 10) * 262144 + t * 1024 + (n & 1023)];
        }
        __syncthreads();
        if (t < 16) szs[t] = np_pairwise_sumsq(&zl[t * 258]);

        float bd0 = 3.4e38f, bd1 = 3.4e38f; int bk0 = 0x7fffffff, bk1 = 0x7fffffff;
        for (int tile = 0; tile < 32; tile++) {
            __syncthreads();
            #pragma unroll
            for (int i = 0; i < 8; i++) {
                int chunk = i * 256 + t;
                int row = chunk >> 6, x = chunk & 63;
                float4 v = *(const float4*)(E + (tile * 32 + row) * 256 + x * 4);
                float* d = &els[row * 258 + x * 4];
                d[0] = v.x; d[1] = v.y; d[2] = v.z; d[3] = v.w;
            }
            __syncthreads();
            int k = tile * 32 + kk;
            const float* e  = &els[kk * 258];
            const float* za = &zl[rr * 258];
            const float* zb = &zl[(rr + 8) * 258];
            float a0 = 0.f, a1 = 0.f;
            for (int c = 0; c < 256; c += 2) {
                float2 e2 = *(const float2*)(e + c);
                float2 x2 = *(const float2*)(za + c);
                float2 y2 = *(const float2*)(zb + c);
                a0 = __fmaf_rn(x2.x, e2.x, a0); a0 = __fmaf_rn(x2.y, e2.y, a0);
                a1 = __fmaf_rn(y2.x, e2.x, a1); a1 = __fmaf_rn(y2.y, e2.y, a1);
            }
            float sek = Se[k];
            float d0 = __fsub_rn(__fadd_rn(szs[rr], sek),     __fmul_rn(2.f, a0));
            float d1 = __fsub_rn(__fadd_rn(szs[rr + 8], sek), __fmul_rn(2.f, a1));
            if (d0 < bd0) { bd0 = d0; bk0 = k; }
            if (d1 < bd1) { bd1 = d1; bk1 = k; }
        }
        #pragma unroll
        for (int mask = 1; mask < 32; mask <<= 1) {
            float od = __shfl_xor(bd0, mask); int ok = __shfl_xor(bk0, mask);
            if (od < bd0 || (od == bd0 && ok < bk0)) { bd0 = od; bk0 = ok; }
            od = __shfl_xor(bd1, mask); ok = __shfl_xor(bk1, mask);
            if (od < bd1 || (od == bd1 && ok < bk1)) { bd1 = od; bk1 = ok; }
        }
        if (kk == 0) {
            if (rr < nrows) idx_out[rowid[rr]] = bk0;
            if (rr + 8 < nrows) idx_out[rowid[rr + 8]] = bk1;
        }
    }
}

// ---------------- kernel 4: gather z_q (f32 out), fused loss ----------------
__global__ __launch_bounds__(256) void gather_loss(const float* __restrict__ Z,
                                                   const float* __restrict__ E,
                                                   const int* __restrict__ idx,
                                                   float* __restrict__ out,
                                                   float* __restrict__ loss) {
    __shared__ int nl[1024];
    __shared__ float rs[256];
    const int t = threadIdx.x;
    const int blk = blockIdx.x;
    const int e0 = blk * 8192;
    const int b = blk >> 5;
    #pragma unroll
    for (int i = 0; i < 4; i++) nl[t + i * 256] = idx[b * 1024 + t + i * 256];
    __syncthreads();
    float ls = 0.f;
    #pragma unroll 4
    for (int i = 0; i < 32; i++) {
        int e = e0 + i * 256 + t;
        int hw = e & 1023;
        int c  = (e >> 10) & 255;
        float q = E[nl[hw] * 256 + c];
        out[e] = q;
        float d = q - Z[e];
        ls += d * d;
    }
    rs[t] = ls; __syncthreads();
    for (int s = 128; s > 0; s >>= 1) { if (t < s) rs[t] += rs[t + s]; __syncthreads(); }
    if (t == 0) atomicAdd(loss, rs[0]);
}

// ---------------- kernel 5: finalize loss + indices i32 -> float in place ----------------
__global__ __launch_bounds__(256) void finalize(const float* __restrict__ loss,
                                                float* __restrict__ out) {
    int g = blockIdx.x * 256 + threadIdx.x;
    if (g == 0) out[16777216] = 1.25f * (*loss) / 16777216.f;
    int raw = ((const int*)(out + IDX_OFF))[g];
    out[IDX_OFF + g] = b2f(f2b((float)raw));  // bf16 round-trip matches bf16-cast ref
}

extern "C" void kernel_launch(void* const* d_in, const int* in_sizes, int n_in,
                              void* d_out, int out_size, void* d_ws, size_t ws_size,
                              hipStream_t stream) {
    const float* Z = (const float*)d_in[0];
    const float* E = (const float*)d_in[1];
    float* out = (float*)d_out;
    char* ws = (char*)d_ws;
    float*        loss = (float*)ws;
    unsigned int* cnt  = (unsigned int*)(ws + 4);
    float*        Se   = (float*)(ws + 64);
    int*          list = (int*)(ws + 4352);
    int*          idx  = (int*)(out + IDX_OFF);
    // bf16 fragment-ordered E lives in the z_q output region (512 KiB),
    // consumed by gemm_argmin, overwritten afterwards by gather_loss.
    unsigned short* Ebf = (unsigned short*)out;

    hipMemsetAsync(ws, 0, 8, stream);
    convert_e<<<128, 256, 0, stream>>>(E, Ebf, Se);
    gemm_argmin<<<1024, 256, 0, stream>>>(Z, Ebf, E, Se, idx, list, cnt);
    refine_full<<<256, 256, 0, stream>>>(Z, E, Se, cnt, list, idx);
    gather_loss<<<2048, 256, 0, stream>>>(Z, E, idx, out, loss);
    finalize<<<256, 256, 0, stream>>>(loss, out);
}

// Round 4
// 413.358 us; speedup vs baseline: 1.5559x; 1.1904x over previous
//
#include <hip/hip_runtime.h>
#include <hip/hip_bf16.h>

// VectorQuantizer on MI355X (gfx950). Inputs fp32, output buffer fp32.
// z: [64,256,32,32] f32; E: [1024,256] f32.
// out (f32): z_q[16777216] | loss[1] | indices[65536] (float(idx), bf16-roundtrip)
//
// R10 (on R9's LDS-resident-Z structure, validated):
//  - eval dot: er loads vectorized float4 + 2-buffer register pipeline (static
//    indices); FMA order c=0..255 unchanged -> bit-identical. Se via LDS Sel.
//  - B stream quad-buffered (issue distance 3 COMPUTEs ~450cyc covers L2
//    latency). COMPUTE order q ascending unchanged -> identical scores.
//  - gather_loss: stage E[:, c0..c0+7] (36KB padded) in LDS; row-gather from
//    LDS instead of 64-way L2 gather. Same per-thread element order.
// Scores bit-identical to R6..R9 -> margin/ballot/refine machinery verbatim.
//
// ws: [0,4) loss f32 | [4,8) full cnt | [64,4160) Se[1024] | [4352,+32K) full list

typedef __attribute__((ext_vector_type(8))) short short8;
typedef __attribute__((ext_vector_type(4))) float floatx4;

#define MARGIN 2.5e-4f
#define FULL_CAP 8192u
#define IDX_OFF 16777217

__device__ __forceinline__ unsigned short f2b(float f) {
    union { float f; unsigned int i; } x; x.f = f;
    unsigned int i = x.i;
    unsigned int r = (i + 0x7fffu + ((i >> 16) & 1u)) >> 16;  // RN-even
    return (unsigned short)r;
}
__device__ __forceinline__ float b2f(unsigned short u) {
    union { unsigned int i; float f; } x; x.i = ((unsigned int)u) << 16; return x.f;
}
__device__ __forceinline__ unsigned int bf2bits(__hip_bfloat162 h) {
    union { __hip_bfloat162 h; unsigned int u; } x; x.h = h; return x.u;
}

// numpy pairwise sum of squares, n=256 contiguous: 128+128, each with 8
// stride-8 accumulators, combine ((r0+r1)+(r2+r3))+((r4+r5)+(r6+r7)).
__device__ __forceinline__ float np_pairwise_sumsq(const float* __restrict__ a) {
    float blk[2];
    #pragma unroll
    for (int h = 0; h < 2; h++) {
        const float* p = a + h * 128;
        float r0 = __fmul_rn(p[0], p[0]), r1 = __fmul_rn(p[1], p[1]);
        float r2 = __fmul_rn(p[2], p[2]), r3 = __fmul_rn(p[3], p[3]);
        float r4 = __fmul_rn(p[4], p[4]), r5 = __fmul_rn(p[5], p[5]);
        float r6 = __fmul_rn(p[6], p[6]), r7 = __fmul_rn(p[7], p[7]);
        for (int i = 8; i < 128; i += 8) {
            r0 = __fadd_rn(r0, __fmul_rn(p[i + 0], p[i + 0]));
            r1 = __fadd_rn(r1, __fmul_rn(p[i + 1], p[i + 1]));
            r2 = __fadd_rn(r2, __fmul_rn(p[i + 2], p[i + 2]));
            r3 = __fadd_rn(r3, __fmul_rn(p[i + 3], p[i + 3]));
            r4 = __fadd_rn(r4, __fmul_rn(p[i + 4], p[i + 4]));
            r5 = __fadd_rn(r5, __fmul_rn(p[i + 5], p[i + 5]));
            r6 = __fadd_rn(r6, __fmul_rn(p[i + 6], p[i + 6]));
            r7 = __fadd_rn(r7, __fmul_rn(p[i + 7], p[i + 7]));
        }
        blk[h] = __fadd_rn(__fadd_rn(__fadd_rn(r0, r1), __fadd_rn(r2, r3)),
                           __fadd_rn(__fadd_rn(r4, r5), __fadd_rn(r6, r7)));
    }
    return __fadd_rn(blk[0], blk[1]);
}

// same summation tree, element c at a[c*64] (LDS [c][x] layout, fixed x)
__device__ __forceinline__ float np_pairwise_sumsq_s64(const float* __restrict__ a) {
    float blk[2];
    #pragma unroll
    for (int h = 0; h < 2; h++) {
        const float* p = a + h * 128 * 64;
        float r0 = __fmul_rn(p[0 * 64], p[0 * 64]), r1 = __fmul_rn(p[1 * 64], p[1 * 64]);
        float r2 = __fmul_rn(p[2 * 64], p[2 * 64]), r3 = __fmul_rn(p[3 * 64], p[3 * 64]);
        float r4 = __fmul_rn(p[4 * 64], p[4 * 64]), r5 = __fmul_rn(p[5 * 64], p[5 * 64]);
        float r6 = __fmul_rn(p[6 * 64], p[6 * 64]), r7 = __fmul_rn(p[7 * 64], p[7 * 64]);
        for (int i = 8; i < 128; i += 8) {
            r0 = __fadd_rn(r0, __fmul_rn(p[(i + 0) * 64], p[(i + 0) * 64]));
            r1 = __fadd_rn(r1, __fmul_rn(p[(i + 1) * 64], p[(i + 1) * 64]));
            r2 = __fadd_rn(r2, __fmul_rn(p[(i + 2) * 64], p[(i + 2) * 64]));
            r3 = __fadd_rn(r3, __fmul_rn(p[(i + 3) * 64], p[(i + 3) * 64]));
            r4 = __fadd_rn(r4, __fmul_rn(p[(i + 4) * 64], p[(i + 4) * 64]));
            r5 = __fadd_rn(r5, __fmul_rn(p[(i + 5) * 64], p[(i + 5) * 64]));
            r6 = __fadd_rn(r6, __fmul_rn(p[(i + 6) * 64], p[(i + 6) * 64]));
            r7 = __fadd_rn(r7, __fmul_rn(p[(i + 7) * 64], p[(i + 7) * 64]));
        }
        blk[h] = __fadd_rn(__fadd_rn(__fadd_rn(r0, r1), __fadd_rn(r2, r3)),
                           __fadd_rn(__fadd_rn(r4, r5), __fadd_rn(r6, r7)));
    }
    return __fadd_rn(blk[0], blk[1]);
}

// ---------------- kernel 1: E f32 -> bf16 fragment order, + Se ----------------
// convert: element (n,k) -> group g = ((nt*4+nf)*8+ks)*4+hi, slot lo*8+j
// (layout validated R7/R8). Blocks 0-3 additionally compute Se[k] np-exact.
__global__ __launch_bounds__(256) void convert_e(const float* __restrict__ E,
                                                 unsigned short* __restrict__ Ebf,
                                                 float* __restrict__ Se) {
    int t = blockIdx.x * 256 + threadIdx.x;
    int n = t >> 5;
    int oct = t & 31;                 // k-octet: k = oct*8 + j ; ks=oct>>2, hi=oct&3
    int nt = n >> 6, nf = (n >> 4) & 3, lo = n & 15;
    int g = ((nt * 4 + nf) * 8 + (oct >> 2)) * 4 + (oct & 3);
    const float* src = E + n * 256 + oct * 8;
    union { short8 s; unsigned int d[4]; } u;
    #pragma unroll
    for (int j = 0; j < 4; j++)
        u.d[j] = bf2bits(__float22bfloat162_rn(make_float2(src[2 * j], src[2 * j + 1])));
    *(short8*)(Ebf + g * 128 + lo * 8) = u.s;
    if (blockIdx.x < 4) {
        int k = blockIdx.x * 256 + threadIdx.x;
        Se[k] = np_pairwise_sumsq(E + k * 256);
    }
}

// ---------------- kernel 2: bf16 MFMA GEMM + exact candidate argmin ----------------
// 1024 blocks (64 z-rows each), 256 threads = 4 waves, 16 rows/wave.
// Z slab (64 rows x 256 ch fp32 = 64KB) + Se (4KB) + szs in static LDS.
__global__ __launch_bounds__(256) void gemm_argmin(const float* __restrict__ Z,
                                                   const unsigned short* __restrict__ Ebf,
                                                   const float* __restrict__ E,
                                                   const float* __restrict__ Se,
                                                   int* __restrict__ idx_out,
                                                   int* __restrict__ full_list,
                                                   unsigned int* __restrict__ full_cnt) {
    __shared__ __align__(16) float Zl[16384];   // [c][x]: c*64 + x, 64KB
    __shared__ __align__(16) float Sel[1024];
    __shared__ float szs[64];
    const int t  = threadIdx.x;
    const int w  = t >> 6;
    const int l  = t & 63;
    const int lo = l & 15;
    const int hi = l >> 4;
    const int m0 = blockIdx.x * 64;
    const int b  = m0 >> 10;                    // 64 | 1024: never crosses b
    const int hwb = m0 & 1023;
    const float* Zb = Z + (size_t)b * 262144;

    // stage Zl: 64 slots of 1KB (4 ch-rows x 256B); wave w takes slots w+4j.
    // lane l: ch = slot*4 + (l>>4), x = (l&15)*4; dest = slot*1024 + l*16 (linear).
    #pragma unroll
    for (int j = 0; j < 16; j++) {
        int iw = w + j * 4;
        __builtin_amdgcn_global_load_lds(
            (const __attribute__((address_space(1))) unsigned int*)
                (Zb + (iw * 4 + hi) * 1024 + hwb + lo * 4),
            (__attribute__((address_space(3))) unsigned int*)((char*)Zl + iw * 1024),
            16, 0, 0);
    }
    // stage Se: wave w stages floats [w*256, w*256+256)
    __builtin_amdgcn_global_load_lds(
        (const __attribute__((address_space(1))) unsigned int*)(Se + w * 256 + l * 4),
        (__attribute__((address_space(3))) unsigned int*)((char*)Sel + w * 1024),
        16, 0, 0);
    asm volatile("s_waitcnt vmcnt(0)" ::: "memory");
    __syncthreads();

    // B-fragment stream from L2-resident Ebf (validated layout): fragment
    // (q,ks) = 1KB at (q*8+ks)*1024 bytes, lane slice +l*16.
    const unsigned short* ebl = Ebf + l * 8;

#define LOADB(buf, q_)                                                         \
    {                                                                          \
        const unsigned short* p_ = ebl + (size_t)(q_) * 4096;                  \
        _Pragma("unroll")                                                      \
        for (int ks = 0; ks < 8; ks++) buf[ks] = *(const short8*)(p_ + ks * 512); \
    }

#define COMPUTE(buf, q_)                                                       \
    {                                                                          \
        float hse = 0.5f * Sel[(q_) * 16 + lo];                                \
        floatx4 a0 = (floatx4){0.f, 0.f, 0.f, 0.f};                            \
        _Pragma("unroll")                                                      \
        for (int ks = 0; ks < 8; ks++)                                         \
            a0 = __builtin_amdgcn_mfma_f32_16x16x32_bf16(af[ks], buf[ks], a0, 0, 0, 0); \
        int n = (q_) * 16 + lo;                                                \
        _Pragma("unroll")                                                      \
        for (int r = 0; r < 4; r++) {                                          \
            float s0 = a0[r] - hse;                                            \
            if (s0 > v1[r])      { v2[r] = v1[r]; v1[r] = s0; i1[r] = n; }     \
            else if (s0 > v2[r]) { v2[r] = s0; }                               \
        }                                                                      \
    }

    short8 bA[8], bB[8], bC[8], bD[8];
    // prologue B loads issued early so L2 latency hides under szs/af work
    LOADB(bA, 0)
    LOADB(bB, 1)
    LOADB(bC, 2)

    // per-row np-exact Sz (same pairwise tree), wave 0: row t
    if (t < 64) szs[t] = np_pairwise_sumsq_s64(Zl + t);

    // A-fragments from LDS: A[m=lo][k=hi*8+j], same cvt pairing -> same bits
    short8 af[8];
    {
        const float* zr = Zl + w * 16 + lo;
        #pragma unroll
        for (int ks = 0; ks < 8; ks++) {
            union { short8 s; unsigned int d[4]; } u;
            #pragma unroll
            for (int j = 0; j < 4; j++) {
                int k = ks * 32 + hi * 8 + 2 * j;
                u.d[j] = bf2bits(__float22bfloat162_rn(
                    make_float2(zr[k * 64], zr[(k + 1) * 64])));
            }
            af[ks] = u.s;
        }
    }

    float v1[4], v2[4]; int i1[4];
    #pragma unroll
    for (int r = 0; r < 4; r++) { v1[r] = -1e30f; v2[r] = -1e30f; i1[r] = 0; }

    // quad-buffered stream: issue-to-use distance = 3 COMPUTEs (~450cyc)
    #pragma unroll 1
    for (int q = 0; q < 64; q += 4) {
        LOADB(bD, q + 3)
        COMPUTE(bA, q)
        if (q + 4 < 64) LOADB(bA, q + 4)
        COMPUTE(bB, q + 1)
        if (q + 5 < 64) LOADB(bB, q + 5)
        COMPUTE(bC, q + 2)
        if (q + 6 < 64) LOADB(bC, q + 6)
        COMPUTE(bD, q + 3)
    }
#undef LOADB
#undef COMPUTE

    __syncthreads();   // szs visibility before eval (uniform control flow)

    // per output row: merged top-1, ballots, candidate resolution (verbatim
    // R6/R9 logic; z-reads LDS, Sz precomputed, er float4-pipelined — same bits)
    #pragma unroll 1
    for (int r = 0; r < 4; r++) {
        float a1v = v1[r]; int ai = i1[r];
        #pragma unroll
        for (int mask = 1; mask < 16; mask <<= 1) {
            float o1 = __shfl_xor(a1v, mask);
            int   oi = __shfl_xor(ai, mask);
            if (o1 > a1v || (o1 == a1v && oi < ai)) { a1v = o1; ai = oi; }
        }
        float thresh = a1v - MARGIN;
        unsigned long long balF = __ballot(v2[r] >= thresh);
        unsigned long long balC = __ballot(v1[r] >= thresh);
        unsigned int fullq = (unsigned int)(balF >> (hi * 16)) & 0xFFFFu;
        unsigned int cm    = (unsigned int)(balC >> (hi * 16)) & 0xFFFFu;
        int m = __popc(cm);
        int rl  = w * 16 + hi * 4 + r;
        int row = m0 + rl;

        if (fullq) {
            // a lane may hide a 3rd+ candidate: full np-exact refine later
            if (lo == 0) {
                idx_out[row] = ai;  // placeholder, overwritten by refine_full
                unsigned int p = atomicAdd(full_cnt, 1u);
                if (p < FULL_CAP) full_list[p] = row;
            }
        } else if (m <= 1) {
            if (lo == 0) idx_out[row] = ai;
        } else {
            // candidate set == lane-top1s within margin (complete: any other k
            // would force its lane's top2 over thresh -> fullq). np-exact:
            // Sz precomputed (same pairwise tree), dot sequential FMA c=0..255
            // (order unchanged; er loads float4 + 2-buffer register pipeline).
            const float* zrow = Zl + rl;
            const float4* er4 = (const float4*)(E + (size_t)i1[r] * 256);
            float dot = 0.f;
            float4 eA[8], eB[8];
            #pragma unroll
            for (int u = 0; u < 8; u++) eA[u] = er4[u];
            #pragma unroll
            for (int half = 0; half < 4; half++) {
                #pragma unroll
                for (int u = 0; u < 8; u++) eB[u] = er4[(2 * half + 1) * 8 + u];
                #pragma unroll
                for (int u = 0; u < 8; u++) {
                    int c = half * 64 + u * 4;
                    dot = __fmaf_rn(zrow[(c + 0) * 64], eA[u].x, dot);
                    dot = __fmaf_rn(zrow[(c + 1) * 64], eA[u].y, dot);
                    dot = __fmaf_rn(zrow[(c + 2) * 64], eA[u].z, dot);
                    dot = __fmaf_rn(zrow[(c + 3) * 64], eA[u].w, dot);
                }
                if (half < 3) {
                    #pragma unroll
                    for (int u = 0; u < 8; u++) eA[u] = er4[(2 * half + 2) * 8 + u];
                }
                #pragma unroll
                for (int u = 0; u < 8; u++) {
                    int c = half * 64 + 32 + u * 4;
                    dot = __fmaf_rn(zrow[(c + 0) * 64], eB[u].x, dot);
                    dot = __fmaf_rn(zrow[(c + 1) * 64], eB[u].y, dot);
                    dot = __fmaf_rn(zrow[(c + 2) * 64], eB[u].z, dot);
                    dot = __fmaf_rn(zrow[(c + 3) * 64], eB[u].w, dot);
                }
            }
            float Sz = szs[rl];
            float dmy = 3.4e38f; int ky = 0x7fffffff;
            if ((cm >> lo) & 1u) {
                dmy = __fsub_rn(__fadd_rn(Sz, Sel[i1[r]]), __fmul_rn(2.f, dot));
                ky = i1[r];
            }
            #pragma unroll
            for (int mask = 1; mask < 16; mask <<= 1) {
                float od = __shfl_xor(dmy, mask);
                int   ok = __shfl_xor(ky, mask);
                if (od < dmy || (od == dmy && ok < ky)) { dmy = od; ky = ok; }
            }
            if (lo == 0) idx_out[row] = ky;
        }
    }
}

// ---------------- kernel 3: LDS-staged full np-exact refine ----------------
// 16 rows per group; E staged in 32-row fp32 LDS tiles; stride 258 (2-way
// bank alias only). k ascending per thread, (d,k) lexicographic reduce ->
// np.argmin first-index semantics.
__global__ __launch_bounds__(256) void refine_full(const float* __restrict__ Z,
                                                   const float* __restrict__ E,
                                                   const float* __restrict__ Se,
                                                   const unsigned int* __restrict__ cnt,
                                                   const int* __restrict__ list,
                                                   int* __restrict__ idx_out) {
    __shared__ float zl[16 * 258];
    __shared__ float els[32 * 258];
    __shared__ float szs[16];
    __shared__ int rowid[16];
    unsigned int C = *cnt;
    if (C > FULL_CAP) C = FULL_CAP;
    const int t = threadIdx.x;
    const int kk = t & 31, rr = t >> 5;
    for (unsigned int base = blockIdx.x * 16; base < C; base += gridDim.x * 16) {
        int nrows = min(16, (int)(C - base));
        __syncthreads();
        if (t < 16) rowid[t] = list[base + (t < nrows ? t : 0)];
        __syncthreads();
        for (int i = 0; i < 16; i++) {
            int n = rowid[i];
            zl[i * 258 + t] = Z[(size_t)(n >> 10) * 262144 + t * 1024 + (n & 1023)];
        }
        __syncthreads();
        if (t < 16) szs[t] = np_pairwise_sumsq(&zl[t * 258]);

        float bd0 = 3.4e38f, bd1 = 3.4e38f; int bk0 = 0x7fffffff, bk1 = 0x7fffffff;
        for (int tile = 0; tile < 32; tile++) {
            __syncthreads();
            #pragma unroll
            for (int i = 0; i < 8; i++) {
                int chunk = i * 256 + t;
                int row = chunk >> 6, x = chunk & 63;
                float4 v = *(const float4*)(E + (tile * 32 + row) * 256 + x * 4);
                float* d = &els[row * 258 + x * 4];
                d[0] = v.x; d[1] = v.y; d[2] = v.z; d[3] = v.w;
            }
            __syncthreads();
            int k = tile * 32 + kk;
            const float* e  = &els[kk * 258];
            const float* za = &zl[rr * 258];
            const float* zb = &zl[(rr + 8) * 258];
            float a0 = 0.f, a1 = 0.f;
            for (int c = 0; c < 256; c += 2) {
                float2 e2 = *(const float2*)(e + c);
                float2 x2 = *(const float2*)(za + c);
                float2 y2 = *(const float2*)(zb + c);
                a0 = __fmaf_rn(x2.x, e2.x, a0); a0 = __fmaf_rn(x2.y, e2.y, a0);
                a1 = __fmaf_rn(y2.x, e2.x, a1); a1 = __fmaf_rn(y2.y, e2.y, a1);
            }
            float sek = Se[k];
            float d0 = __fsub_rn(__fadd_rn(szs[rr], sek),     __fmul_rn(2.f, a0));
            float d1 = __fsub_rn(__fadd_rn(szs[rr + 8], sek), __fmul_rn(2.f, a1));
            if (d0 < bd0) { bd0 = d0; bk0 = k; }
            if (d1 < bd1) { bd1 = d1; bk1 = k; }
        }
        #pragma unroll
        for (int mask = 1; mask < 32; mask <<= 1) {
            float od = __shfl_xor(bd0, mask); int ok = __shfl_xor(bk0, mask);
            if (od < bd0 || (od == bd0 && ok < bk0)) { bd0 = od; bk0 = ok; }
            od = __shfl_xor(bd1, mask); ok = __shfl_xor(bk1, mask);
            if (od < bd1 || (od == bd1 && ok < bk1)) { bd1 = od; bk1 = ok; }
        }
        if (kk == 0) {
            if (rr < nrows) idx_out[rowid[rr]] = bk0;
            if (rr + 8 < nrows) idx_out[rowid[rr + 8]] = bk1;
        }
    }
}

// ---------------- kernel 4: gather z_q (f32 out), fused loss ----------------
// E columns c0..c0+7 staged in LDS (pad *9 -> 2-way max on write, random-bank
// on gather) -> removes the 64-way L2 row-gather per wave instruction.
__global__ __launch_bounds__(256) void gather_loss(const float* __restrict__ Z,
                                                   const float* __restrict__ E,
                                                   const int* __restrict__ idx,
                                                   float* __restrict__ out,
                                                   float* __restrict__ loss) {
    __shared__ int nl[1024];
    __shared__ float Ecol[1024 * 9];   // 36KB
    __shared__ float rs[256];
    const int t = threadIdx.x;
    const int blk = blockIdx.x;
    const int e0 = blk * 8192;
    const int b = blk >> 5;
    const int c0 = (blk & 31) * 8;     // (e0>>10)&255
    #pragma unroll
    for (int i = 0; i < 4; i++) nl[t + i * 256] = idx[b * 1024 + t + i * 256];
    #pragma unroll
    for (int i = 0; i < 4; i++) {
        int k = i * 256 + t;
        const float4* src = (const float4*)(E + k * 256 + c0);
        float4 v0 = src[0], v1 = src[1];
        float* d = &Ecol[k * 9];
        d[0] = v0.x; d[1] = v0.y; d[2] = v0.z; d[3] = v0.w;
        d[4] = v1.x; d[5] = v1.y; d[6] = v1.z; d[7] = v1.w;
    }
    __syncthreads();
    float ls = 0.f;
    #pragma unroll 4
    for (int i = 0; i < 32; i++) {
        int off = i * 256 + t;
        int hw = off & 1023;
        int coff = off >> 10;          // 0..7
        float q = Ecol[nl[hw] * 9 + coff];
        int e = e0 + off;
        out[e] = q;
        float d = q - Z[e];
        ls += d * d;
    }
    rs[t] = ls; __syncthreads();
    for (int s = 128; s > 0; s >>= 1) { if (t < s) rs[t] += rs[t + s]; __syncthreads(); }
    if (t == 0) atomicAdd(loss, rs[0]);
}

// ---------------- kernel 5: finalize loss + indices i32 -> float in place ----------------
__global__ __launch_bounds__(256) void finalize(const float* __restrict__ loss,
                                                float* __restrict__ out) {
    int g = blockIdx.x * 256 + threadIdx.x;
    if (g == 0) out[16777216] = 1.25f * (*loss) / 16777216.f;
    int raw = ((const int*)(out + IDX_OFF))[g];
    out[IDX_OFF + g] = b2f(f2b((float)raw));  // bf16 round-trip matches bf16-cast ref
}

extern "C" void kernel_launch(void* const* d_in, const int* in_sizes, int n_in,
                              void* d_out, int out_size, void* d_ws, size_t ws_size,
                              hipStream_t stream) {
    const float* Z = (const float*)d_in[0];
    const float* E = (const float*)d_in[1];
    float* out = (float*)d_out;
    char* ws = (char*)d_ws;
    float*        loss = (float*)ws;
    unsigned int* cnt  = (unsigned int*)(ws + 4);
    float*        Se   = (float*)(ws + 64);
    int*          list = (int*)(ws + 4352);
    int*          idx  = (int*)(out + IDX_OFF);
    // bf16 fragment-ordered E lives in the z_q output region (512 KiB),
    // consumed by gemm_argmin, overwritten afterwards by gather_loss.
    unsigned short* Ebf = (unsigned short*)out;

    hipMemsetAsync(ws, 0, 8, stream);
    convert_e<<<128, 256, 0, stream>>>(E, Ebf, Se);
    gemm_argmin<<<1024, 256, 0, stream>>>(Z, Ebf, E, Se, idx, list, cnt);
    refine_full<<<256, 256, 0, stream>>>(Z, E, Se, cnt, list, idx);
    gather_loss<<<2048, 256, 0, stream>>>(Z, E, idx, out, loss);
    finalize<<<256, 256, 0, stream>>>(loss, out);
}